// Round 7
// baseline (153.280 us; speedup 1.0000x reference)
//
#include <hip/hip_runtime.h>
#include <math.h>

// Problem constants (reference: N=32, K=16, BINS=100, DIM=2, sample_size=100)
#define NBINS 100
#define NN    32
#define KD    16
#define NT    99    // sample_size-1

// ws float offsets
#define OFF_H   0        // h[p][j][d] 100*16*2 = 3200
#define OFF_QT  3200     // qt[j][n] = Q[n][j]  16*32 = 512
#define OFF_XL  3712     // x_last 64
#define OFF_C   3776     // c_j = sigma^-2 * mu_j (16)
#define OFF_P   3792     // [0]=sigma_sq_inv

// ---------------- f64 cross-lane primitives (VALU-only, no DS) -------------
template<int CTRL>
__device__ __forceinline__ double dmov_dpp(double x) {
  union { double d; int i[2]; } u, r;
  u.d = x;
  r.i[0] = __builtin_amdgcn_update_dpp(0, u.i[0], CTRL, 0xf, 0xf, true);
  r.i[1] = __builtin_amdgcn_update_dpp(0, u.i[1], CTRL, 0xf, 0xf, true);
  return r.d;
}
__device__ __forceinline__ double drdlane(double x, int lane) {
  union { double d; int i[2]; } u;
  u.d = x;
  u.i[0] = __builtin_amdgcn_readlane(u.i[0], lane);
  u.i[1] = __builtin_amdgcn_readlane(u.i[1], lane);
  return u.d;
}
// whole-wave shift-up-by-1: out[l] = in[l-1], out[0] = c0  (row_shr:1 + fixups)
__device__ __forceinline__ double dshup(double x, double c0, int lane) {
  double v = dmov_dpp<0x111>(x);
  double x15 = drdlane(x, 15), x31 = drdlane(x, 31), x47 = drdlane(x, 47);
  v = (lane == 0)  ? c0  : v;
  v = (lane == 16) ? x15 : v;
  v = (lane == 32) ? x31 : v;
  v = (lane == 48) ? x47 : v;
  return v;
}
// element k (0..99) from (lo,hi) register pair; k wave-uniform
__device__ __forceinline__ double rdpos(double lo, double hi, int k) {
  return (k < 64) ? drdlane(lo, k) : drdlane(hi, k - 64);
}

// ====================== K0: eig(C^T C) + Q + params (1 wave) ===============
// Single wave: xor-pair tournament (masks 1..15 cover all 120 pairs),
// 5 sweeps, 3 single-wave fences/round. Also x_last.
__global__ __launch_bounds__(64) void k0_eig(
    const float* __restrict__ x0, const float* __restrict__ v,
    const float* __restrict__ sigma_in, const float* __restrict__ Cq,
    float* __restrict__ ws)
{
  __shared__ double A[16][17], Vv[16][17];
  __shared__ double csC[8], csS[8];
  __shared__ float CqS[NN * KD];
  const int l = threadIdx.x;
  float sig = fmaxf(sigma_in[0], 0.05f);          // clip(sigma, 5/BINS)
  const double sinvd = 1.0 / ((double)sig * (double)sig);

  for (int e = l; e < NN * KD; e += 64) CqS[e] = Cq[e];

  {                                                // x_last
    float acc = 0.f;
    for (int p = 0; p < NBINS; ++p) acc += v[p * 64 + l];
    ws[OFF_XL + l] = x0[l] + 0.01f * acc;
  }
  __syncthreads();

  for (int e = l; e < 256; e += 64) {              // G = Cq^T Cq, V = I
    int k1 = e >> 4, k2 = e & 15;
    double acc = 0.0;
    for (int n = 0; n < NN; ++n)
      acc += (double)CqS[n * 16 + k1] * (double)CqS[n * 16 + k2];
    A[k1][k2] = acc;
    Vv[k1][k2] = (k1 == k2) ? 1.0 : 0.0;
  }
  __syncthreads();

  for (int sweep = 0; sweep < 5; ++sweep)
  for (int m = 1; m <= 15; ++m) {
    const int hb = 31 - __clz(m);
    const int lowm = (1 << hb) - 1;
    if (l < 8) {                                   // c,s per pair
      int p = ((l & ~lowm) << 1) | (l & lowm), q = p ^ m;
      double app = A[p][p], aqq = A[q][q], apq = A[p][q];
      double c = 1.0, s = 0.0;
      if (fabs(apq) > 1e-300) {
        double th = (aqq - app) / (2.0 * apq);
        double t_ = ((th >= 0.0) ? 1.0 : -1.0) / (fabs(th) + sqrt(th * th + 1.0));
        c = 1.0 / sqrt(t_ * t_ + 1.0);
        s = t_ * c;
      }
      csC[l] = c; csS[l] = s;
    }
    __syncthreads();
    #pragma unroll
    for (int rep = 0; rep < 2; ++rep) {            // rows of A (128 items)
      int e = l + rep * 64;
      int t = e >> 4, rc = e & 15;
      int p = ((t & ~lowm) << 1) | (t & lowm), q = p ^ m;
      double c = csC[t], s = csS[t];
      double ap = A[p][rc], aq = A[q][rc];
      A[p][rc] = c * ap - s * aq;
      A[q][rc] = s * ap + c * aq;
    }
    __syncthreads();
    #pragma unroll
    for (int rep = 0; rep < 4; ++rep) {            // cols of A + V (256 items)
      int e = l + rep * 64;
      int t2 = e & 127, t = t2 >> 4, rc = t2 & 15;
      int p = ((t & ~lowm) << 1) | (t & lowm), q = p ^ m;
      double c = csC[t], s = csS[t];
      if (e < 128) {
        double ap = A[rc][p], aq = A[rc][q];
        A[rc][p] = c * ap - s * aq;
        A[rc][q] = s * ap + c * aq;
      } else {
        double vp = Vv[rc][p], vq = Vv[rc][q];
        Vv[rc][p] = c * vp - s * vq;
        Vv[rc][q] = s * vp + c * vq;
      }
    }
    __syncthreads();
  }

  if (l < 16) {
    double mu = A[l][l];
    if (mu < 0.0) mu = 0.0;
    ws[OFF_C + l] = (float)(sinvd * mu);
  }
  if (l == 0) ws[OFF_P + 0] = (float)sinvd;
  for (int e = l; e < 512; e += 64) {              // QT[j][n] = (C*U)[n][j]
    int jq = e >> 5, n = e & 31;
    double acc = 0.0;
    for (int k2 = 0; k2 < 16; ++k2)
      acc += (double)CqS[n * 16 + k2] * Vv[k2][jq];
    ws[OFF_QT + e] = (float)acc;
  }
}

// ========== K1: per-eigenvalue Toeplitz solve via SCHUR (no reductions) ====
// 16 blocks x 1 wave. Solve (I + c_j*T) x = s_j (2 RHS) for M~ Toeplitz:
// generator recursion gamma_k = v[k+1]/u[k] (readlane + div only), forward
// solve by residual update (no inner products), L~ rows streamed to LDS,
// backward solve reads contiguous rows with prefetch. All f64.
__global__ __launch_bounds__(64) void k1_schur(
    const float* __restrict__ v_in, const float* __restrict__ ls_in,
    float* __restrict__ ws)
{
  extern __shared__ double dsm[];
  double* Lrow  = dsm;                         // 100*101
  double* sdInv = Lrow + 100 * 101;            // 100
  float*  vT    = (float*)(sdInv + 100);       // 64*101
  float*  qs    = vT + 64 * 101;               // 32

  const int l = threadIdx.x;
  const int j = blockIdx.x;
  const double c = (double)ws[OFF_C + j];
  const double sinvd = (double)ws[OFF_P + 0];
  const float ls = ls_in[0];
  const float i2 = -0.5f / (ls * ls);
  const int ahi = 64 + l;
  const bool hiv = (ahi < 100);

  for (int p = 0; p < NBINS; ++p) vT[l * 101 + p] = v_in[p * 64 + l];
  if (l < 32) qs[l] = ws[OFF_QT + j * 32 + l];
  __syncthreads();

  // s at p = l (lo) and p = 64+l (hi)
  float s0l = 0.f, s1l = 0.f, s0h = 0.f, s1h = 0.f;
  for (int n = 0; n < NN; ++n) {
    float qv = qs[n];
    s0l += qv * vT[(2 * n) * 101 + l];
    s1l += qv * vT[(2 * n + 1) * 101 + l];
    if (hiv) {
      s0h += qv * vT[(2 * n) * 101 + ahi];
      s1h += qv * vT[(2 * n + 1) * 101 + ahi];
    }
  }

  // normalized Toeplitz first column t_k = c*g_k/m0 ; b = s/m0
  const double m0  = 1.0 + c * (1.0 + 1e-5);
  const double im0 = 1.0 / m0;
  float gl = expf((0.01f * (float)l) * (0.01f * (float)l) * i2);
  float gh = expf((0.01f * (float)ahi) * (0.01f * (float)ahi) * i2);
  double u_lo = (l == 0) ? 1.0 : c * (double)gl * im0;
  double u_hi = hiv ? c * (double)gh * im0 : 0.0;
  double v_lo = (l == 0) ? 0.0 : u_lo;          // v = (0, t1, ..)
  double v_hi = u_hi;
  double r0_lo = (double)s0l * im0, r1_lo = (double)s1l * im0;
  double r0_hi = hiv ? (double)s0h * im0 : 0.0;
  double r1_hi = hiv ? (double)s1h * im0 : 0.0;
  double P = 1.0;

  // ---- forward: Schur recursion + residual solve + L~ row streaming ----
  for (int k = 0; k < 100; ++k) {
    double uk  = rdpos(u_lo, u_hi, k);
    double iuk = 1.0 / uk;
    double r0k = rdpos(r0_lo, r0_hi, k);
    double r1k = rdpos(r1_lo, r1_hi, k);
    // L~[:,k] stored by rows: Lrow[pos][k] = u[pos]*iuk
    Lrow[l * 101 + k] = u_lo * iuk;
    if (hiv) Lrow[ahi * 101 + k] = u_hi * iuk;
    if (l == 0) sdInv[k] = P * iuk * iuk;       // 1/d_k
    double a0 = r0k * iuk, a1 = r1k * iuk;
    if (l > k)   { r0_lo -= a0 * u_lo; r1_lo -= a1 * u_lo; }
    if (ahi > k) { r0_hi -= a0 * u_hi; r1_hi -= a1 * u_hi; }
    if (k < 99) {
      double vk1 = rdpos(v_lo, v_hi, k + 1);
      double g = vk1 * iuk;
      double u63 = drdlane(u_lo, 63);
      double u1_lo = dshup(u_lo, 0.0, l);       // Z u
      double u1_hi = dshup(u_hi, u63, l);
      u_lo = u1_lo - g * v_lo;  u_hi = u1_hi - g * v_hi;
      v_lo = v_lo - g * u1_lo;  v_hi = v_hi - g * u1_hi;
      P *= (1.0 - g * g);
    }
  }
  __syncthreads();                               // Lrow/sdInv visible

  // ---- diagonal scale: w = y / d ----
  double sd_l = sdInv[l];
  double sd_h = hiv ? sdInv[ahi] : 0.0;
  double x0_lo = r0_lo * sd_l, x1_lo = r1_lo * sd_l;
  double x0_hi = r0_hi * sd_h, x1_hi = r1_hi * sd_h;

  // ---- backward: L~^T x = w, residual update with row reads (prefetched) --
  double Ll = Lrow[99 * 101 + l];
  double Lh = hiv ? Lrow[99 * 101 + ahi] : 0.0;
  for (int k = 99; k >= 1; --k) {
    double nLl = Lrow[(k - 1) * 101 + l];
    double nLh = hiv ? Lrow[(k - 1) * 101 + ahi] : 0.0;
    double xk0 = rdpos(x0_lo, x0_hi, k);
    double xk1 = rdpos(x1_lo, x1_hi, k);
    if (l < k)   { x0_lo -= xk0 * Ll; x1_lo -= xk1 * Ll; }
    if (ahi < k) { x0_hi -= xk0 * Lh; x1_hi -= xk1 * Lh; }
    Ll = nLl; Lh = nLh;
  }

  // h[p][j][d] = sinv * x[p]
  ws[OFF_H + l * 32 + j * 2 + 0] = (float)(sinvd * x0_lo);
  ws[OFF_H + l * 32 + j * 2 + 1] = (float)(sinvd * x1_lo);
  if (hiv) {
    ws[OFF_H + ahi * 32 + j * 2 + 0] = (float)(sinvd * x0_hi);
    ws[OFF_H + ahi * 32 + j * 2 + 1] = (float)(sinvd * x1_hi);
  }
}

// =============================== K_TAIL ====================================
// 16 blocks x 256: stage h/Q^T/xl, Bc table, z = Bc*h, xt, intensity pairs.
#define L_H   0        // 3200
#define L_QT  3200     // 512
#define L_XL  3712     // 64
#define L_BC  3776     // 99*100 = 9900
#define L_Z   13676    // 99*32  = 3168
#define L_XT  16844    // 99*64  = 6336
#define L_PS  23180    // 4*64   = 256
#define L_TOT 23436

__global__ __launch_bounds__(256) void k_tail(
    const float* __restrict__ ls_in, const float* __restrict__ beta,
    const float* __restrict__ ws, float* __restrict__ out)
{
  extern __shared__ float lds[];
  const int tid = threadIdx.x;
  const float ls = ls_in[0];
  const float i2 = -0.5f / (ls * ls);

  for (int e = tid; e < 3200; e += 256) lds[L_H + e] = ws[OFF_H + e];
  for (int e = tid; e < 512; e += 256)  lds[L_QT + e] = ws[OFF_QT + e];
  if (tid < 64) lds[L_XL + tid] = ws[OFF_XL + tid];
  for (int e = tid; e < NT * NBINS; e += 256) {
    int t = e / NBINS, p = e - t * NBINS;
    float tst = 1.0f + (float)t * (1.0f / 99.0f);
    float dd = tst - ((float)p + 0.5f) * 0.01f;
    lds[L_BC + e] = expf(dd * dd * i2);
  }
  __syncthreads();

  // z[t][j][d] = sum_p Bc[t][p] * h[p][j][d]
  for (int dot = tid; dot < NT * 32; dot += 256) {
    int t = dot >> 5, jd = dot & 31;
    float acc = 0.f;
    for (int p = 0; p < NBINS; ++p)
      acc += lds[L_BC + t * NBINS + p] * lds[L_H + p * 32 + jd];
    lds[L_Z + dot] = acc;
  }
  __syncthreads();

  // xt[t][n][d] = xl[nd] + trel * sum_j qt[j][n] * z[t][j][d]
  for (int e = tid; e < NT * 64; e += 256) {
    int t = e >> 6, nd = e & 63, n = nd >> 1, d = nd & 1;
    float acc = 0.f;
    for (int jq = 0; jq < 16; ++jq)
      acc += lds[L_QT + jq * 32 + n] * lds[L_Z + t * 32 + jq * 2 + d];
    float trel = (float)t * (1.0f / 99.0f);
    lds[L_XT + e] = lds[L_XL + nd] + trel * acc;
  }
  __syncthreads();

  // intensity: 64 pairs per block, 4-way t-split
  {
    const int pl = tid & 63, tc = tid >> 6;
    const int gp = blockIdx.x * 64 + pl;
    const int i = gp >> 5, jj = gp & 31;
    const float bsum = beta[i] + beta[jj];
    const int t0 = tc * 25, t1 = (t0 + 25 < NT) ? t0 + 25 : NT;
    float acc = 0.f;
    for (int t = t0; t < t1; ++t) {
      float2 xi = *(const float2*)&lds[L_XT + t * 64 + 2 * i];
      float2 xj = *(const float2*)&lds[L_XT + t * 64 + 2 * jj];
      float dx = xi.x - xj.x, dy = xi.y - xj.y;
      float sq = fmaxf(dx * dx + dy * dy, 1e-12f);
      acc += expf(bsum - sqrtf(sq));
    }
    lds[L_PS + tc * 64 + pl] = acc;
  }
  __syncthreads();
  if (tid < 64) {
    float s = lds[L_PS + tid] + lds[L_PS + 64 + tid]
            + lds[L_PS + 128 + tid] + lds[L_PS + 192 + tid];
    out[blockIdx.x * 64 + tid] = s * (1.0f / 99.0f);
  }
}

extern "C" void kernel_launch(void* const* d_in, const int* in_sizes, int n_in,
                              void* d_out, int out_size, void* d_ws, size_t ws_size,
                              hipStream_t stream) {
  const float* x0    = (const float*)d_in[0];
  const float* v     = (const float*)d_in[1];
  const float* beta  = (const float*)d_in[2];
  const float* sigma = (const float*)d_in[3];
  // d_in[4] = x0c: unused (B_cross row 0 is zero)
  const float* ls    = (const float*)d_in[5];
  const float* Cq    = (const float*)d_in[6];
  float* out = (float*)d_out;
  float* ws  = (float*)d_ws;

  k0_eig<<<1, 64, 0, stream>>>(x0, v, sigma, Cq, ws);
  const size_t smem1 = (size_t)(100 * 101 + 100) * sizeof(double)
                     + (size_t)(64 * 101 + 32) * sizeof(float);   // ~105 KB
  k1_schur<<<16, 64, smem1, stream>>>(v, ls, ws);
  k_tail<<<16, 256, (size_t)L_TOT * sizeof(float), stream>>>(ls, beta, ws, out);
}

// Round 8
// 141.600 us; speedup vs baseline: 1.0825x; 1.0825x over previous
//
#include <hip/hip_runtime.h>
#include <math.h>

// Problem constants (reference: N=32, K=16, BINS=100, DIM=2, sample_size=100)
#define NBINS 100
#define NN    32
#define KD    16
#define NT    99    // sample_size-1

// ws float offsets
#define OFF_H   0        // h[p][j][d] 100*16*2 = 3200
#define OFF_QT  3200     // qt[j][n] = Q[n][j]  16*32 = 512
#define OFF_XL  3712     // x_last 64
#define OFF_C   3776     // c_j = sigma^-2 * mu_j (16)
#define OFF_P   3792     // [0]=sigma_sq_inv

// ---------------- f64 cross-lane primitives (VALU-only, no DS) -------------
template<int CTRL>
__device__ __forceinline__ double dmov_dpp(double x) {
  union { double d; int i[2]; } u, r;
  u.d = x;
  r.i[0] = __builtin_amdgcn_update_dpp(0, u.i[0], CTRL, 0xf, 0xf, true);
  r.i[1] = __builtin_amdgcn_update_dpp(0, u.i[1], CTRL, 0xf, 0xf, true);
  return r.d;
}
__device__ __forceinline__ double drdlane(double x, int lane) {
  union { double d; int i[2]; } u;
  u.d = x;
  u.i[0] = __builtin_amdgcn_readlane(u.i[0], lane);
  u.i[1] = __builtin_amdgcn_readlane(u.i[1], lane);
  return u.d;
}
// whole-wave shift-up-by-1: out[l] = in[l-1], out[0] = c0  (row_shr:1 + fixups)
__device__ __forceinline__ double dshup(double x, double c0, int lane) {
  double v = dmov_dpp<0x111>(x);
  double x15 = drdlane(x, 15), x31 = drdlane(x, 31), x47 = drdlane(x, 47);
  v = (lane == 0)  ? c0  : v;
  v = (lane == 16) ? x15 : v;
  v = (lane == 32) ? x31 : v;
  v = (lane == 48) ? x47 : v;
  return v;
}
// element k (0..99) from (lo,hi) register pair; k wave-uniform
__device__ __forceinline__ double rdpos(double lo, double hi, int k) {
  return (k < 64) ? drdlane(lo, k) : drdlane(hi, k - 64);
}
// fast f64 reciprocal: f32 rcp seed + 2 Newton steps (~1 ulp f64)
__device__ __forceinline__ double frcp64(double x) {
  double r = (double)__builtin_amdgcn_rcpf((float)x);
  r = r * (2.0 - x * r);
  r = r * (2.0 - x * r);
  return r;
}

// ====================== K0: eig(C^T C) + Q + params (1 wave, f32) ==========
// Single wave: xor-pair tournament (masks 1..15 cover all 120 pairs),
// 5 sweeps, 3 single-wave fences/round, fast f32 rcp/rsq. Also x_last.
// f32 is ample: output is bf16-compared; U error enters as ~1e-6 relative.
__global__ __launch_bounds__(64) void k0_eig(
    const float* __restrict__ x0, const float* __restrict__ v,
    const float* __restrict__ sigma_in, const float* __restrict__ Cq,
    float* __restrict__ ws)
{
  __shared__ float A[16][17], Vv[16][17];
  __shared__ float csC[8], csS[8];
  __shared__ float CqS[NN * KD];
  const int l = threadIdx.x;
  float sig = fmaxf(sigma_in[0], 0.05f);          // clip(sigma, 5/BINS)
  const double sinvd = 1.0 / ((double)sig * (double)sig);

  for (int e = l; e < NN * KD; e += 64) CqS[e] = Cq[e];

  {                                                // x_last
    float acc = 0.f;
    for (int p = 0; p < NBINS; ++p) acc += v[p * 64 + l];
    ws[OFF_XL + l] = x0[l] + 0.01f * acc;
  }
  __syncthreads();

  for (int e = l; e < 256; e += 64) {              // G = Cq^T Cq, V = I
    int k1 = e >> 4, k2 = e & 15;
    float acc = 0.f;
    for (int n = 0; n < NN; ++n)
      acc += CqS[n * 16 + k1] * CqS[n * 16 + k2];
    A[k1][k2] = acc;
    Vv[k1][k2] = (k1 == k2) ? 1.0f : 0.0f;
  }
  __syncthreads();

  for (int sweep = 0; sweep < 5; ++sweep)
  for (int m = 1; m <= 15; ++m) {
    const int hb = 31 - __clz(m);
    const int lowm = (1 << hb) - 1;
    if (l < 8) {                                   // c,s per pair (fast f32)
      int p = ((l & ~lowm) << 1) | (l & lowm), q = p ^ m;
      float app = A[p][p], aqq = A[q][q], apq = A[p][q];
      float c = 1.0f, s = 0.0f;
      if (fabsf(apq) > 1e-30f) {
        float th = (aqq - app) * 0.5f * __builtin_amdgcn_rcpf(apq);
        float t_ = __builtin_amdgcn_rcpf(fabsf(th) + sqrtf(th * th + 1.0f));
        t_ = (th >= 0.0f) ? t_ : -t_;
        c = __builtin_amdgcn_rsqf(t_ * t_ + 1.0f);
        s = t_ * c;
      }
      csC[l] = c; csS[l] = s;
    }
    __syncthreads();
    #pragma unroll
    for (int rep = 0; rep < 2; ++rep) {            // rows of A (128 items)
      int e = l + rep * 64;
      int t = e >> 4, rc = e & 15;
      int p = ((t & ~lowm) << 1) | (t & lowm), q = p ^ m;
      float c = csC[t], s = csS[t];
      float ap = A[p][rc], aq = A[q][rc];
      A[p][rc] = c * ap - s * aq;
      A[q][rc] = s * ap + c * aq;
    }
    __syncthreads();
    #pragma unroll
    for (int rep = 0; rep < 4; ++rep) {            // cols of A + V (256 items)
      int e = l + rep * 64;
      int t2 = e & 127, t = t2 >> 4, rc = t2 & 15;
      int p = ((t & ~lowm) << 1) | (t & lowm), q = p ^ m;
      float c = csC[t], s = csS[t];
      if (e < 128) {
        float ap = A[rc][p], aq = A[rc][q];
        A[rc][p] = c * ap - s * aq;
        A[rc][q] = s * ap + c * aq;
      } else {
        float vp = Vv[rc][p], vq = Vv[rc][q];
        Vv[rc][p] = c * vp - s * vq;
        Vv[rc][q] = s * vp + c * vq;
      }
    }
    __syncthreads();
  }

  if (l < 16) {
    float mu = A[l][l];
    if (mu < 0.0f) mu = 0.0f;
    ws[OFF_C + l] = (float)(sinvd * (double)mu);
  }
  if (l == 0) ws[OFF_P + 0] = (float)sinvd;
  for (int e = l; e < 512; e += 64) {              // QT[j][n] = (C*U)[n][j]
    int jq = e >> 5, n = e & 31;
    float acc = 0.f;
    for (int k2 = 0; k2 < 16; ++k2)
      acc += CqS[n * 16 + k2] * Vv[k2][jq];
    ws[OFF_QT + e] = acc;
  }
}

// ========== K1: per-eigenvalue Toeplitz solve via SCHUR (no reductions) ====
// 16 blocks x 1 wave. Solve (I + c_j*T) x = s_j (2 RHS) for M~ Toeplitz:
// generator recursion gamma_k = v[k+1]/u[k] (readlane + fast-rcp only),
// forward solve by residual update (no inner products), L~ rows streamed to
// LDS, backward solve reads contiguous rows with prefetch. All f64.
__global__ __launch_bounds__(64) void k1_schur(
    const float* __restrict__ v_in, const float* __restrict__ ls_in,
    float* __restrict__ ws)
{
  extern __shared__ double dsm[];
  double* Lrow  = dsm;                         // 100*101
  double* sdInv = Lrow + 100 * 101;            // 100
  float*  vT    = (float*)(sdInv + 100);       // 64*101
  float*  qs    = vT + 64 * 101;               // 32

  const int l = threadIdx.x;
  const int j = blockIdx.x;
  const double c = (double)ws[OFF_C + j];
  const double sinvd = (double)ws[OFF_P + 0];
  const float ls = ls_in[0];
  const float i2 = -0.5f / (ls * ls);
  const int ahi = 64 + l;
  const bool hiv = (ahi < 100);

  for (int p = 0; p < NBINS; ++p) vT[l * 101 + p] = v_in[p * 64 + l];
  if (l < 32) qs[l] = ws[OFF_QT + j * 32 + l];
  __syncthreads();

  // s at p = l (lo) and p = 64+l (hi)
  float s0l = 0.f, s1l = 0.f, s0h = 0.f, s1h = 0.f;
  for (int n = 0; n < NN; ++n) {
    float qv = qs[n];
    s0l += qv * vT[(2 * n) * 101 + l];
    s1l += qv * vT[(2 * n + 1) * 101 + l];
    if (hiv) {
      s0h += qv * vT[(2 * n) * 101 + ahi];
      s1h += qv * vT[(2 * n + 1) * 101 + ahi];
    }
  }

  // normalized Toeplitz first column t_k = c*g_k/m0 ; b = s/m0
  const double m0  = 1.0 + c * (1.0 + 1e-5);
  const double im0 = frcp64(m0);
  float gl = expf((0.01f * (float)l) * (0.01f * (float)l) * i2);
  float gh = expf((0.01f * (float)ahi) * (0.01f * (float)ahi) * i2);
  double u_lo = (l == 0) ? 1.0 : c * (double)gl * im0;
  double u_hi = hiv ? c * (double)gh * im0 : 0.0;
  double v_lo = (l == 0) ? 0.0 : u_lo;          // v = (0, t1, ..)
  double v_hi = u_hi;
  double r0_lo = (double)s0l * im0, r1_lo = (double)s1l * im0;
  double r0_hi = hiv ? (double)s0h * im0 : 0.0;
  double r1_hi = hiv ? (double)s1h * im0 : 0.0;
  double P = 1.0;

  // ---- forward: Schur recursion + residual solve + L~ row streaming ----
  for (int k = 0; k < 100; ++k) {
    double uk  = rdpos(u_lo, u_hi, k);
    double iuk = frcp64(uk);
    double r0k = rdpos(r0_lo, r0_hi, k);
    double r1k = rdpos(r1_lo, r1_hi, k);
    // L~[:,k] stored by rows: Lrow[pos][k] = u[pos]*iuk
    Lrow[l * 101 + k] = u_lo * iuk;
    if (hiv) Lrow[ahi * 101 + k] = u_hi * iuk;
    if (l == 0) sdInv[k] = P * iuk * iuk;       // 1/d_k
    double a0 = r0k * iuk, a1 = r1k * iuk;
    if (l > k)   { r0_lo -= a0 * u_lo; r1_lo -= a1 * u_lo; }
    if (ahi > k) { r0_hi -= a0 * u_hi; r1_hi -= a1 * u_hi; }
    if (k < 99) {
      double vk1 = rdpos(v_lo, v_hi, k + 1);
      double g = vk1 * iuk;
      double u63 = drdlane(u_lo, 63);
      double u1_lo = dshup(u_lo, 0.0, l);       // Z u
      double u1_hi = dshup(u_hi, u63, l);
      u_lo = u1_lo - g * v_lo;  u_hi = u1_hi - g * v_hi;
      v_lo = v_lo - g * u1_lo;  v_hi = v_hi - g * u1_hi;
      P *= (1.0 - g * g);
    }
  }
  __syncthreads();                               // Lrow/sdInv visible

  // ---- diagonal scale: w = y / d ----
  double sd_l = sdInv[l];
  double sd_h = hiv ? sdInv[ahi] : 0.0;
  double x0_lo = r0_lo * sd_l, x1_lo = r1_lo * sd_l;
  double x0_hi = r0_hi * sd_h, x1_hi = r1_hi * sd_h;

  // ---- backward: L~^T x = w, residual update with row reads (prefetched) --
  double Ll = Lrow[99 * 101 + l];
  double Lh = hiv ? Lrow[99 * 101 + ahi] : 0.0;
  for (int k = 99; k >= 1; --k) {
    double nLl = Lrow[(k - 1) * 101 + l];
    double nLh = hiv ? Lrow[(k - 1) * 101 + ahi] : 0.0;
    double xk0 = rdpos(x0_lo, x0_hi, k);
    double xk1 = rdpos(x1_lo, x1_hi, k);
    if (l < k)   { x0_lo -= xk0 * Ll; x1_lo -= xk1 * Ll; }
    if (ahi < k) { x0_hi -= xk0 * Lh; x1_hi -= xk1 * Lh; }
    Ll = nLl; Lh = nLh;
  }

  // h[p][j][d] = sinv * x[p]
  ws[OFF_H + l * 32 + j * 2 + 0] = (float)(sinvd * x0_lo);
  ws[OFF_H + l * 32 + j * 2 + 1] = (float)(sinvd * x1_lo);
  if (hiv) {
    ws[OFF_H + ahi * 32 + j * 2 + 0] = (float)(sinvd * x0_hi);
    ws[OFF_H + ahi * 32 + j * 2 + 1] = (float)(sinvd * x1_hi);
  }
}

// =============================== K_TAIL ====================================
// 16 blocks x 256: stage h/Q^T/xl, Bc table, z = Bc*h, xt, intensity pairs.
#define L_H   0        // 3200
#define L_QT  3200     // 512
#define L_XL  3712     // 64
#define L_BC  3776     // 99*100 = 9900
#define L_Z   13676    // 99*32  = 3168
#define L_XT  16844    // 99*64  = 6336
#define L_PS  23180    // 4*64   = 256
#define L_TOT 23436

__global__ __launch_bounds__(256) void k_tail(
    const float* __restrict__ ls_in, const float* __restrict__ beta,
    const float* __restrict__ ws, float* __restrict__ out)
{
  extern __shared__ float lds[];
  const int tid = threadIdx.x;
  const float ls = ls_in[0];
  const float i2 = -0.5f / (ls * ls);

  for (int e = tid; e < 3200; e += 256) lds[L_H + e] = ws[OFF_H + e];
  for (int e = tid; e < 512; e += 256)  lds[L_QT + e] = ws[OFF_QT + e];
  if (tid < 64) lds[L_XL + tid] = ws[OFF_XL + tid];
  for (int e = tid; e < NT * NBINS; e += 256) {
    int t = e / NBINS, p = e - t * NBINS;
    float tst = 1.0f + (float)t * (1.0f / 99.0f);
    float dd = tst - ((float)p + 0.5f) * 0.01f;
    lds[L_BC + e] = expf(dd * dd * i2);
  }
  __syncthreads();

  // z[t][j][d] = sum_p Bc[t][p] * h[p][j][d]
  for (int dot = tid; dot < NT * 32; dot += 256) {
    int t = dot >> 5, jd = dot & 31;
    float acc = 0.f;
    for (int p = 0; p < NBINS; ++p)
      acc += lds[L_BC + t * NBINS + p] * lds[L_H + p * 32 + jd];
    lds[L_Z + dot] = acc;
  }
  __syncthreads();

  // xt[t][n][d] = xl[nd] + trel * sum_j qt[j][n] * z[t][j][d]
  for (int e = tid; e < NT * 64; e += 256) {
    int t = e >> 6, nd = e & 63, n = nd >> 1, d = nd & 1;
    float acc = 0.f;
    for (int jq = 0; jq < 16; ++jq)
      acc += lds[L_QT + jq * 32 + n] * lds[L_Z + t * 32 + jq * 2 + d];
    float trel = (float)t * (1.0f / 99.0f);
    lds[L_XT + e] = lds[L_XL + nd] + trel * acc;
  }
  __syncthreads();

  // intensity: 64 pairs per block, 4-way t-split
  {
    const int pl = tid & 63, tc = tid >> 6;
    const int gp = blockIdx.x * 64 + pl;
    const int i = gp >> 5, jj = gp & 31;
    const float bsum = beta[i] + beta[jj];
    const int t0 = tc * 25, t1 = (t0 + 25 < NT) ? t0 + 25 : NT;
    float acc = 0.f;
    for (int t = t0; t < t1; ++t) {
      float2 xi = *(const float2*)&lds[L_XT + t * 64 + 2 * i];
      float2 xj = *(const float2*)&lds[L_XT + t * 64 + 2 * jj];
      float dx = xi.x - xj.x, dy = xi.y - xj.y;
      float sq = fmaxf(dx * dx + dy * dy, 1e-12f);
      acc += expf(bsum - sqrtf(sq));
    }
    lds[L_PS + tc * 64 + pl] = acc;
  }
  __syncthreads();
  if (tid < 64) {
    float s = lds[L_PS + tid] + lds[L_PS + 64 + tid]
            + lds[L_PS + 128 + tid] + lds[L_PS + 192 + tid];
    out[blockIdx.x * 64 + tid] = s * (1.0f / 99.0f);
  }
}

extern "C" void kernel_launch(void* const* d_in, const int* in_sizes, int n_in,
                              void* d_out, int out_size, void* d_ws, size_t ws_size,
                              hipStream_t stream) {
  const float* x0    = (const float*)d_in[0];
  const float* v     = (const float*)d_in[1];
  const float* beta  = (const float*)d_in[2];
  const float* sigma = (const float*)d_in[3];
  // d_in[4] = x0c: unused (B_cross row 0 is zero)
  const float* ls    = (const float*)d_in[5];
  const float* Cq    = (const float*)d_in[6];
  float* out = (float*)d_out;
  float* ws  = (float*)d_ws;

  k0_eig<<<1, 64, 0, stream>>>(x0, v, sigma, Cq, ws);
  const size_t smem1 = (size_t)(100 * 101 + 100) * sizeof(double)
                     + (size_t)(64 * 101 + 32) * sizeof(float);   // ~105 KB
  k1_schur<<<16, 64, smem1, stream>>>(v, ls, ws);
  k_tail<<<16, 256, (size_t)L_TOT * sizeof(float), stream>>>(ls, beta, ws, out);
}

// Round 9
// 121.938 us; speedup vs baseline: 1.2570x; 1.1612x over previous
//
#include <hip/hip_runtime.h>
#include <math.h>

// Problem constants (reference: N=32, K=16, BINS=100, DIM=2, sample_size=100)
#define NBINS 100
#define NN    32
#define KD    16
#define NT    99    // sample_size-1

// ws float offsets
#define OFF_H   0        // h[p][j][d] 100*16*2 = 3200
#define OFF_QT  3200     // qt[j][n] = Q[n][j]  16*32 = 512
#define OFF_XL  3712     // x_last 64
#define OFF_C   3776     // c_j = sigma^-2 * mu_j (16)
#define OFF_P   3792     // [0]=sigma_sq_inv

// ---------------- f32 cross-lane primitives (VALU-only, no DS) -------------
template<int CTRL>
__device__ __forceinline__ float fmov_dpp(float x) {
  return __int_as_float(
      __builtin_amdgcn_update_dpp(0, __float_as_int(x), CTRL, 0xf, 0xf, true));
}
__device__ __forceinline__ float frdlane(float x, int lane) {
  return __int_as_float(__builtin_amdgcn_readlane(__float_as_int(x), lane));
}
// whole-wave shift-up-by-1: out[l] = in[l-1], out[0] = c0  (row_shr:1 + fixups)
__device__ __forceinline__ float fshup(float x, float c0, int lane) {
  float v = fmov_dpp<0x111>(x);
  float x15 = frdlane(x, 15), x31 = frdlane(x, 31), x47 = frdlane(x, 47);
  v = (lane == 0)  ? c0  : v;
  v = (lane == 16) ? x15 : v;
  v = (lane == 32) ? x31 : v;
  v = (lane == 48) ? x47 : v;
  return v;
}
// element k (0..99) from (lo,hi) register pair; k wave-uniform
__device__ __forceinline__ float frdpos(float lo, float hi, int k) {
  return (k < 64) ? frdlane(lo, k) : frdlane(hi, k - 64);
}
// fast f32 reciprocal: HW rcp + 1 Newton step (~1 ulp)
__device__ __forceinline__ float frcp(float x) {
  float r = __builtin_amdgcn_rcpf(x);
  return r * (2.0f - x * r);
}

// ====================== K0: eig(C^T C) + Q + params (1 wave, f32) ==========
// Fused one-phase Jacobi: A'' = J^T A J computed elementwise; each lane owns
// 4 A-elements (r = l>>2, c = (l&3)+4k) + 4 V-elements. Per round: (c,s)
// table -> batched reads (no interleaved writes => fully pipelined) ->
// barrier -> writes. xor-pair tournament masks m=1..15, 5 sweeps.
__global__ __launch_bounds__(64) void k0_eig(
    const float* __restrict__ x0, const float* __restrict__ v,
    const float* __restrict__ sigma_in, const float* __restrict__ Cq,
    float* __restrict__ ws)
{
  __shared__ float A[16 * 17], Vv[16 * 17];
  __shared__ float csC[16], csS[16];
  __shared__ float CqS[NN * KD];
  const int l = threadIdx.x;
  const int r = l >> 2, c0 = l & 3;
  float sig = fmaxf(sigma_in[0], 0.05f);          // clip(sigma, 5/BINS)
  const double sinvd = 1.0 / ((double)sig * (double)sig);

  for (int e = l; e < NN * KD; e += 64) CqS[e] = Cq[e];

  {                                                // x_last
    float acc = 0.f;
    for (int p = 0; p < NBINS; ++p) acc += v[p * 64 + l];
    ws[OFF_XL + l] = x0[l] + 0.01f * acc;
  }
  __syncthreads();

  #pragma unroll
  for (int k = 0; k < 4; ++k) {                    // G = Cq^T Cq, V = I
    int c = c0 + 4 * k;
    float acc = 0.f;
    for (int n = 0; n < NN; ++n)
      acc += CqS[n * 16 + r] * CqS[n * 16 + c];
    A[r * 17 + c] = acc;
    Vv[r * 17 + c] = (r == c) ? 1.0f : 0.0f;
  }
  __syncthreads();

  for (int sweep = 0; sweep < 5; ++sweep)
  for (int m = 1; m <= 15; ++m) {
    const int hb = 31 - __clz(m);
    const int lowm = (1 << hb) - 1;
    if (l < 8) {                                   // (c,s) per pair
      int p = ((l & ~lowm) << 1) | (l & lowm), q = p ^ m;
      float app = A[p * 17 + p], aqq = A[q * 17 + q], apq = A[p * 17 + q];
      float c = 1.0f, s = 0.0f;
      if (fabsf(apq) > 1e-30f) {
        float th = (aqq - app) * 0.5f * __builtin_amdgcn_rcpf(apq);
        float t_ = __builtin_amdgcn_rcpf(fabsf(th) + sqrtf(th * th + 1.0f));
        t_ = (th >= 0.0f) ? t_ : -t_;
        c = __builtin_amdgcn_rsqf(t_ * t_ + 1.0f);
        s = t_ * c;
      }
      csC[p] = c; csS[p] = -s;
      csC[q] = c; csS[q] = s;
    }
    __syncthreads();
    // batched reads (4 A-quads + 2 V-pairs per lane), then barrier, then write
    const int rh = r ^ m;
    float ar = csC[r], br = csS[r];
    float nA[4], nV[4];
    #pragma unroll
    for (int k = 0; k < 4; ++k) {
      int ci = c0 + 4 * k, ch = ci ^ m;
      float ac = csC[ci], bc = csS[ci];
      float a_rc = A[r * 17 + ci],  a_hc = A[rh * 17 + ci];
      float a_rh = A[r * 17 + ch],  a_hh = A[rh * 17 + ch];
      float v_rc = Vv[r * 17 + ci], v_rh = Vv[r * 17 + ch];
      nA[k] = ac * (ar * a_rc + br * a_hc) + bc * (ar * a_rh + br * a_hh);
      nV[k] = ac * v_rc + bc * v_rh;
    }
    __syncthreads();                               // all reads done
    #pragma unroll
    for (int k = 0; k < 4; ++k) {
      int ci = c0 + 4 * k;
      A[r * 17 + ci] = nA[k];
      Vv[r * 17 + ci] = nV[k];
    }
    __syncthreads();
  }

  if (l < 16) {
    float mu = A[l * 17 + l];
    if (mu < 0.0f) mu = 0.0f;
    ws[OFF_C + l] = (float)(sinvd * (double)mu);
  }
  if (l == 0) ws[OFF_P + 0] = (float)sinvd;
  for (int e = l; e < 512; e += 64) {              // QT[j][n] = (C*U)[n][j]
    int jq = e >> 5, n = e & 31;
    float acc = 0.f;
    for (int k2 = 0; k2 < 16; ++k2)
      acc += CqS[n * 16 + k2] * Vv[k2 * 17 + jq];
    ws[OFF_QT + e] = acc;
  }
}

// ========== K1: per-eigenvalue Toeplitz solve via SCHUR (f32, no DS loop) ==
// 16 blocks x 1 wave. Solve (I + c_j*T) x = s_j (2 RHS), T Toeplitz.
// Generator recursion: readlane + 1-instr rcp only; forward solve by residual
// update (no inner products); L~ rows streamed to LDS; backward solve reads
// contiguous rows with prefetch. f32 (cond ~1e4; output is bf16-compared).
__global__ __launch_bounds__(64) void k1_schur(
    const float* __restrict__ v_in, const float* __restrict__ ls_in,
    float* __restrict__ ws)
{
  extern __shared__ float fsm[];
  float* Lrow  = fsm;                          // 100*101
  float* sdInv = Lrow + 100 * 101;             // 100
  float* vT    = sdInv + 100;                  // 64*101
  float* qs    = vT + 64 * 101;                // 32

  const int l = threadIdx.x;
  const int j = blockIdx.x;
  const float c = ws[OFF_C + j];
  const float sinvf = ws[OFF_P + 0];
  const float ls = ls_in[0];
  const float i2 = -0.5f / (ls * ls);
  const int ahi = 64 + l;
  const bool hiv = (ahi < 100);

  for (int p = 0; p < NBINS; ++p) vT[l * 101 + p] = v_in[p * 64 + l];
  if (l < 32) qs[l] = ws[OFF_QT + j * 32 + l];
  __syncthreads();

  // s at p = l (lo) and p = 64+l (hi)
  float s0l = 0.f, s1l = 0.f, s0h = 0.f, s1h = 0.f;
  for (int n = 0; n < NN; ++n) {
    float qv = qs[n];
    s0l += qv * vT[(2 * n) * 101 + l];
    s1l += qv * vT[(2 * n + 1) * 101 + l];
    if (hiv) {
      s0h += qv * vT[(2 * n) * 101 + ahi];
      s1h += qv * vT[(2 * n + 1) * 101 + ahi];
    }
  }

  // normalized Toeplitz first column t_k = c*g_k/m0 ; b = s/m0
  const float m0  = 1.0f + c * (1.0f + 1e-5f);
  const float im0 = frcp(m0);
  float gl = expf((0.01f * (float)l) * (0.01f * (float)l) * i2);
  float gh = expf((0.01f * (float)ahi) * (0.01f * (float)ahi) * i2);
  float u_lo = (l == 0) ? 1.0f : c * gl * im0;
  float u_hi = hiv ? c * gh * im0 : 0.0f;
  float v_lo = (l == 0) ? 0.0f : u_lo;          // v = (0, t1, ..)
  float v_hi = u_hi;
  float r0_lo = s0l * im0, r1_lo = s1l * im0;
  float r0_hi = hiv ? s0h * im0 : 0.0f;
  float r1_hi = hiv ? s1h * im0 : 0.0f;
  float P = 1.0f;

  // ---- forward: Schur recursion + residual solve + L~ row streaming ----
  for (int k = 0; k < 100; ++k) {
    float uk  = frdpos(u_lo, u_hi, k);
    float iuk = frcp(uk);
    float r0k = frdpos(r0_lo, r0_hi, k);
    float r1k = frdpos(r1_lo, r1_hi, k);
    Lrow[l * 101 + k] = u_lo * iuk;             // L~[:,k] stored by rows
    if (hiv) Lrow[ahi * 101 + k] = u_hi * iuk;
    if (l == 0) sdInv[k] = P * iuk * iuk;       // 1/d_k
    float a0 = r0k * iuk, a1 = r1k * iuk;
    if (l > k)   { r0_lo -= a0 * u_lo; r1_lo -= a1 * u_lo; }
    if (ahi > k) { r0_hi -= a0 * u_hi; r1_hi -= a1 * u_hi; }
    if (k < 99) {
      float vk1 = frdpos(v_lo, v_hi, k + 1);
      float g = vk1 * iuk;
      float u63 = frdlane(u_lo, 63);
      float u1_lo = fshup(u_lo, 0.0f, l);       // Z u
      float u1_hi = fshup(u_hi, u63, l);
      u_lo = u1_lo - g * v_lo;  u_hi = u1_hi - g * v_hi;
      v_lo = v_lo - g * u1_lo;  v_hi = v_hi - g * u1_hi;
      P *= (1.0f - g * g);
    }
  }
  __syncthreads();                               // Lrow/sdInv visible

  // ---- diagonal scale: w = y / d ----
  float sd_l = sdInv[l];
  float sd_h = hiv ? sdInv[ahi] : 0.0f;
  float x0_lo = r0_lo * sd_l, x1_lo = r1_lo * sd_l;
  float x0_hi = r0_hi * sd_h, x1_hi = r1_hi * sd_h;

  // ---- backward: L~^T x = w, residual update with row reads (prefetched) --
  float Ll = Lrow[99 * 101 + l];
  float Lh = hiv ? Lrow[99 * 101 + ahi] : 0.0f;
  for (int k = 99; k >= 1; --k) {
    float nLl = Lrow[(k - 1) * 101 + l];
    float nLh = hiv ? Lrow[(k - 1) * 101 + ahi] : 0.0f;
    float xk0 = frdpos(x0_lo, x0_hi, k);
    float xk1 = frdpos(x1_lo, x1_hi, k);
    if (l < k)   { x0_lo -= xk0 * Ll; x1_lo -= xk1 * Ll; }
    if (ahi < k) { x0_hi -= xk0 * Lh; x1_hi -= xk1 * Lh; }
    Ll = nLl; Lh = nLh;
  }

  // h[p][j][d] = sinv * x[p]
  ws[OFF_H + l * 32 + j * 2 + 0] = sinvf * x0_lo;
  ws[OFF_H + l * 32 + j * 2 + 1] = sinvf * x1_lo;
  if (hiv) {
    ws[OFF_H + ahi * 32 + j * 2 + 0] = sinvf * x0_hi;
    ws[OFF_H + ahi * 32 + j * 2 + 1] = sinvf * x1_hi;
  }
}

// =============================== K_TAIL ====================================
// 16 blocks x 256: stage h/Q^T/xl, Bc table, z = Bc*h, xt, intensity pairs.
#define L_H   0        // 3200
#define L_QT  3200     // 512
#define L_XL  3712     // 64
#define L_BC  3776     // 99*100 = 9900
#define L_Z   13676    // 99*32  = 3168
#define L_XT  16844    // 99*64  = 6336
#define L_PS  23180    // 4*64   = 256
#define L_TOT 23436

__global__ __launch_bounds__(256) void k_tail(
    const float* __restrict__ ls_in, const float* __restrict__ beta,
    const float* __restrict__ ws, float* __restrict__ out)
{
  extern __shared__ float lds[];
  const int tid = threadIdx.x;
  const float ls = ls_in[0];
  const float i2 = -0.5f / (ls * ls);

  for (int e = tid; e < 3200; e += 256) lds[L_H + e] = ws[OFF_H + e];
  for (int e = tid; e < 512; e += 256)  lds[L_QT + e] = ws[OFF_QT + e];
  if (tid < 64) lds[L_XL + tid] = ws[OFF_XL + tid];
  for (int e = tid; e < NT * NBINS; e += 256) {
    int t = e / NBINS, p = e - t * NBINS;
    float tst = 1.0f + (float)t * (1.0f / 99.0f);
    float dd = tst - ((float)p + 0.5f) * 0.01f;
    lds[L_BC + e] = expf(dd * dd * i2);
  }
  __syncthreads();

  // z[t][j][d] = sum_p Bc[t][p] * h[p][j][d]
  for (int dot = tid; dot < NT * 32; dot += 256) {
    int t = dot >> 5, jd = dot & 31;
    float acc = 0.f;
    for (int p = 0; p < NBINS; ++p)
      acc += lds[L_BC + t * NBINS + p] * lds[L_H + p * 32 + jd];
    lds[L_Z + dot] = acc;
  }
  __syncthreads();

  // xt[t][n][d] = xl[nd] + trel * sum_j qt[j][n] * z[t][j][d]
  for (int e = tid; e < NT * 64; e += 256) {
    int t = e >> 6, nd = e & 63, n = nd >> 1, d = nd & 1;
    float acc = 0.f;
    for (int jq = 0; jq < 16; ++jq)
      acc += lds[L_QT + jq * 32 + n] * lds[L_Z + t * 32 + jq * 2 + d];
    float trel = (float)t * (1.0f / 99.0f);
    lds[L_XT + e] = lds[L_XL + nd] + trel * acc;
  }
  __syncthreads();

  // intensity: 64 pairs per block, 4-way t-split
  {
    const int pl = tid & 63, tc = tid >> 6;
    const int gp = blockIdx.x * 64 + pl;
    const int i = gp >> 5, jj = gp & 31;
    const float bsum = beta[i] + beta[jj];
    const int t0 = tc * 25, t1 = (t0 + 25 < NT) ? t0 + 25 : NT;
    float acc = 0.f;
    for (int t = t0; t < t1; ++t) {
      float2 xi = *(const float2*)&lds[L_XT + t * 64 + 2 * i];
      float2 xj = *(const float2*)&lds[L_XT + t * 64 + 2 * jj];
      float dx = xi.x - xj.x, dy = xi.y - xj.y;
      float sq = fmaxf(dx * dx + dy * dy, 1e-12f);
      acc += expf(bsum - sqrtf(sq));
    }
    lds[L_PS + tc * 64 + pl] = acc;
  }
  __syncthreads();
  if (tid < 64) {
    float s = lds[L_PS + tid] + lds[L_PS + 64 + tid]
            + lds[L_PS + 128 + tid] + lds[L_PS + 192 + tid];
    out[blockIdx.x * 64 + tid] = s * (1.0f / 99.0f);
  }
}

extern "C" void kernel_launch(void* const* d_in, const int* in_sizes, int n_in,
                              void* d_out, int out_size, void* d_ws, size_t ws_size,
                              hipStream_t stream) {
  const float* x0    = (const float*)d_in[0];
  const float* v     = (const float*)d_in[1];
  const float* beta  = (const float*)d_in[2];
  const float* sigma = (const float*)d_in[3];
  // d_in[4] = x0c: unused (B_cross row 0 is zero)
  const float* ls    = (const float*)d_in[5];
  const float* Cq    = (const float*)d_in[6];
  float* out = (float*)d_out;
  float* ws  = (float*)d_ws;

  k0_eig<<<1, 64, 0, stream>>>(x0, v, sigma, Cq, ws);
  const size_t smem1 = (size_t)(100 * 101 + 100 + 64 * 101 + 32) * sizeof(float); // ~67 KB
  k1_schur<<<16, 64, smem1, stream>>>(v, ls, ws);
  k_tail<<<16, 256, (size_t)L_TOT * sizeof(float), stream>>>(ls, beta, ws, out);
}